// Round 4
// baseline (606.566 us; speedup 1.0000x reference)
//
#include <hip/hip_runtime.h>

#define D_IN  128
#define D_H   64
#define D_OUT 40

// ---------------- degree / CSR build ----------------

// 8 edges per thread: vector index loads + 8 independent atomics in flight.
__launch_bounds__(256)
static __global__ void k_count(const int* __restrict__ dst, int* __restrict__ deg, int E){
  int base = (blockIdx.x*256 + threadIdx.x) * 8;
  if (base + 8 <= E){
    int4 d0 = *(const int4*)(dst + base);
    int4 d1 = *(const int4*)(dst + base + 4);
    atomicAdd(&deg[d0.x], 1); atomicAdd(&deg[d0.y], 1);
    atomicAdd(&deg[d0.z], 1); atomicAdd(&deg[d0.w], 1);
    atomicAdd(&deg[d1.x], 1); atomicAdd(&deg[d1.y], 1);
    atomicAdd(&deg[d1.z], 1); atomicAdd(&deg[d1.w], 1);
  } else {
    for (int i = base; i < E; i++) atomicAdd(&deg[dst[i]], 1);
  }
}

static __global__ void k_scan1(const int* __restrict__ deg, int* __restrict__ incl,
                               int* __restrict__ bsums, int n){
  __shared__ int s[1024];
  int t = threadIdx.x; int g = blockIdx.x*1024 + t;
  int v = (g < n) ? deg[g] : 0;
  s[t] = v; __syncthreads();
  for (int off = 1; off < 1024; off <<= 1){
    int u = (t >= off) ? s[t-off] : 0; __syncthreads();
    s[t] += u; __syncthreads();
  }
  if (g < n) incl[g] = s[t];
  if (t == 1023) bsums[blockIdx.x] = s[1023];
}

static __global__ void k_scan2(int* bsums, int nb){
  __shared__ int s[128];
  int t = threadIdx.x;
  int v = (t < nb) ? bsums[t] : 0;
  s[t] = v; __syncthreads();
  for (int off = 1; off < 128; off <<= 1){
    int u = (t >= off) ? s[t-off] : 0; __syncthreads();
    s[t] += u; __syncthreads();
  }
  if (t < nb) bsums[t] = s[t] - v;   // exclusive block offsets
}

static __global__ void k_scan3(const int* __restrict__ deg, int* __restrict__ rs,
                               const int* __restrict__ bsums, int* __restrict__ cursor,
                               float* __restrict__ dinv, int n){
  int t = threadIdx.x; int g = blockIdx.x*1024 + t;
  if (g < n){
    int excl = rs[g] - deg[g] + bsums[blockIdx.x];
    rs[g] = excl; cursor[g] = excl;
    dinv[g] = rsqrtf((float)(deg[g] + 1));   // +1 = self loop
  }
}

// 8 edges per thread: 8 independent atomic->store chains pipelined.
__launch_bounds__(256)
static __global__ void k_fill(const int* __restrict__ src, const int* __restrict__ dst,
                              int* __restrict__ cursor, int* __restrict__ col, int E){
  int base = (blockIdx.x*256 + threadIdx.x) * 8;
  if (base + 8 <= E){
    int4 d0 = *(const int4*)(dst + base);
    int4 d1 = *(const int4*)(dst + base + 4);
    int4 s0 = *(const int4*)(src + base);
    int4 s1 = *(const int4*)(src + base + 4);
    int p0 = atomicAdd(&cursor[d0.x], 1);
    int p1 = atomicAdd(&cursor[d0.y], 1);
    int p2 = atomicAdd(&cursor[d0.z], 1);
    int p3 = atomicAdd(&cursor[d0.w], 1);
    int p4 = atomicAdd(&cursor[d1.x], 1);
    int p5 = atomicAdd(&cursor[d1.y], 1);
    int p6 = atomicAdd(&cursor[d1.z], 1);
    int p7 = atomicAdd(&cursor[d1.w], 1);
    col[p0] = s0.x; col[p1] = s0.y; col[p2] = s0.z; col[p3] = s0.w;
    col[p4] = s1.x; col[p5] = s1.y; col[p6] = s1.z; col[p7] = s1.w;
  } else {
    for (int i = base; i < E; i++){ int p = atomicAdd(&cursor[dst[i]], 1); col[p] = src[i]; }
  }
}

// ---------------- fold delete-MLP into GEMM2: M = Wd1^T @ Wc2, bvec = bd1 @ Wc2 -----

static __global__ void k_pre(const float* __restrict__ Wd1, const float* __restrict__ bd1,
                             const float* __restrict__ Wc2, float* __restrict__ M,
                             float* __restrict__ bvec){
  int t = threadIdx.x;
  for (int i = t; i < D_H*D_OUT; i += 256){
    int q = i / D_OUT, j = i % D_OUT;
    float s = 0.f;
    for (int k = 0; k < D_H; k++) s += Wd1[k*D_H + q] * Wc2[k*D_OUT + j];
    M[i] = s;
  }
  if (t < D_OUT){
    float s = 0.f;
    for (int k = 0; k < D_H; k++) s += bd1[k] * Wc2[k*D_OUT + t];
    bvec[t] = s;
  }
}

// ---------------- GEMM1: hws1[n] = dinv[n] * (x[n] @ Wc1) ----------------

__launch_bounds__(256)
static __global__ void k_gemm1(const float* __restrict__ x, const float* __restrict__ Wc1,
                               const float* __restrict__ dinv, float* __restrict__ hws1, int n){
  __shared__ float Wl[D_IN*D_H];        // 32 KB
  __shared__ float xs[32][D_IN+1];      // padded
  int t = threadIdx.x;
  int base = blockIdx.x*32;
  for (int i = t; i < D_IN*D_H; i += 256) Wl[i] = Wc1[i];
  for (int i = t; i < 32*D_IN; i += 256){
    int r = i >> 7, c = i & 127;
    int node = base + r;
    xs[r][c] = (node < n) ? x[(size_t)node*D_IN + c] : 0.f;
  }
  __syncthreads();
  int nl = t >> 3, j0 = (t & 7)*8;
  int node = base + nl;
  if (node >= n) return;
  float acc[8] = {0,0,0,0,0,0,0,0};
  #pragma unroll 4
  for (int k = 0; k < D_IN; k++){
    float xv = xs[nl][k];
    #pragma unroll
    for (int jj = 0; jj < 8; jj++) acc[jj] += xv * Wl[k*D_H + j0 + jj];
  }
  float dv = dinv[node];
  float4 o0 = make_float4(acc[0]*dv, acc[1]*dv, acc[2]*dv, acc[3]*dv);
  float4 o1 = make_float4(acc[4]*dv, acc[5]*dv, acc[6]*dv, acc[7]*dv);
  float* op = hws1 + (size_t)node*D_H + j0;
  *(float4*)op = o0; *(float4*)(op+4) = o1;
}

// ---------------- agg1: h = relu(dinv * (self + sum_in) + bc1) ----------------
// 4 edges gathered per wave-instruction: 4 groups x 16 lanes x float4.

__launch_bounds__(256)
static __global__ void k_agg1(const float* __restrict__ hws1, const int* __restrict__ rs,
                              const int* __restrict__ deg, const int* __restrict__ col,
                              const float* __restrict__ dinv, const float* __restrict__ bc1,
                              float* __restrict__ h, int n){
  int t = threadIdx.x;
  int wave = t >> 6, lane = t & 63;
  int node = blockIdx.x*4 + wave;
  if (node >= n) return;
  int grp = lane >> 4, fl = lane & 15;
  const float4* h4 = (const float4*)hws1;
  float4 acc = make_float4(0.f, 0.f, 0.f, 0.f);
  if (grp == 0) acc = h4[(size_t)node*16 + fl];     // self loop
  int s0 = rs[node], cnt = deg[node];
  for (int cb = 0; cb < cnt; cb += 64){
    int m = cnt - cb; if (m > 64) m = 64;
    int idx = (lane < m) ? col[s0 + cb + lane] : 0;  // coalesced index prefetch
    #pragma unroll 4
    for (int e0 = 0; e0 < m; e0 += 4){
      int sl = e0 + grp;
      int s = __shfl(idx, sl, 64);
      if (sl < m){
        float4 v = h4[(size_t)s*16 + fl];
        acc.x += v.x; acc.y += v.y; acc.z += v.z; acc.w += v.w;
      }
    }
  }
  // combine the 4 groups
  acc.x += __shfl_xor(acc.x, 16, 64); acc.y += __shfl_xor(acc.y, 16, 64);
  acc.z += __shfl_xor(acc.z, 16, 64); acc.w += __shfl_xor(acc.w, 16, 64);
  acc.x += __shfl_xor(acc.x, 32, 64); acc.y += __shfl_xor(acc.y, 32, 64);
  acc.z += __shfl_xor(acc.z, 32, 64); acc.w += __shfl_xor(acc.w, 32, 64);
  if (grp == 0){
    float dv = dinv[node];
    float4 b = ((const float4*)bc1)[fl];
    float4 o;
    o.x = fmaxf(acc.x*dv + b.x, 0.f);
    o.y = fmaxf(acc.y*dv + b.y, 0.f);
    o.z = fmaxf(acc.z*dv + b.z, 0.f);
    o.w = fmaxf(acc.w*dv + b.w, 0.f);
    ((float4*)h)[(size_t)node*16 + fl] = o;
  }
}

// ---------------- GEMM2 (+ folded delete MLP): hws2[n] = dinv[n] * (h[n] @ (mask? M:Wc2)) --

__launch_bounds__(128)
static __global__ void k_gemm2(const float* __restrict__ h, const unsigned char* __restrict__ mask,
                               const float* __restrict__ Mmat, const float* __restrict__ bvec,
                               const float* __restrict__ Wc2, const float* __restrict__ dinv,
                               float* __restrict__ hws2, int n){
  __shared__ float Ms[D_H*D_OUT];          // 10 KB
  __shared__ float Ws[D_H*D_OUT];          // 10 KB
  __shared__ float bv[D_OUT];
  __shared__ float hs[128*(D_H+1)];        // 33.3 KB, padded stride 65
  int t = threadIdx.x;
  int base = blockIdx.x*128;
  for (int i = t; i < D_H*D_OUT; i += 128){ Ms[i] = Mmat[i]; Ws[i] = Wc2[i]; }
  if (t < D_OUT) bv[t] = bvec[t];
  for (int i = t; i < 128*D_H; i += 128){
    int r = i >> 6, c = i & 63;
    int node = base + r;
    hs[r*(D_H+1) + c] = (node < n) ? h[(size_t)node*D_H + c] : 0.f;
  }
  __syncthreads();
  int node = base + t;
  if (node >= n) return;
  bool m = mask[node] != 0;
  const float* Wp = m ? Ms : Ws;
  float acc[D_OUT];
  #pragma unroll
  for (int j = 0; j < D_OUT; j++) acc[j] = m ? bv[j] : 0.f;
  const float* hrow = &hs[t*(D_H+1)];
  for (int q = 0; q < D_H; q++){
    float hv = hrow[q];
    #pragma unroll
    for (int j = 0; j < D_OUT; j++) acc[j] += hv * Wp[q*D_OUT + j];
  }
  float dv = dinv[node];
  float* op = hws2 + (size_t)node*D_OUT;
  #pragma unroll
  for (int j = 0; j < D_OUT; j++) op[j] = acc[j]*dv;
}

// ---------------- agg2 + final delete epilogue -> out ----------------
// Same 4-edges-per-instruction structure; 10 of 16 lanes per group carry float4.

__launch_bounds__(256)
static __global__ void k_agg2(const float* __restrict__ hws2, const int* __restrict__ rs,
                              const int* __restrict__ deg, const int* __restrict__ col,
                              const float* __restrict__ dinv, const float* __restrict__ bc2,
                              const unsigned char* __restrict__ mask,
                              const float* __restrict__ Wd2, const float* __restrict__ bd2,
                              float* __restrict__ out, int n){
  __shared__ float wds[D_OUT*41];          // stride-41 pad -> <=2-way LDS conflict (free)
  __shared__ float bds[D_OUT];
  int t = threadIdx.x;
  for (int i = t; i < D_OUT*D_OUT; i += 256){
    int j = i / D_OUT, k = i % D_OUT;
    wds[j*41 + k] = Wd2[i];
  }
  if (t < D_OUT) bds[t] = bd2[t];
  __syncthreads();
  int wave = t >> 6, lane = t & 63;
  int node = blockIdx.x*4 + wave;
  if (node >= n) return;
  int grp = lane >> 4, fl = lane & 15;
  bool fa = fl < 10;                       // 10 float4 = 40 features
  const float4* h4 = (const float4*)hws2;
  float4 acc = make_float4(0.f, 0.f, 0.f, 0.f);
  if (grp == 0 && fa) acc = h4[(size_t)node*10 + fl];   // self loop
  int s0 = rs[node], cnt = deg[node];
  for (int cb = 0; cb < cnt; cb += 64){
    int m = cnt - cb; if (m > 64) m = 64;
    int idx = (lane < m) ? col[s0 + cb + lane] : 0;
    #pragma unroll 4
    for (int e0 = 0; e0 < m; e0 += 4){
      int sl = e0 + grp;
      int s = __shfl(idx, sl, 64);
      if (sl < m && fa){
        float4 v = h4[(size_t)s*10 + fl];
        acc.x += v.x; acc.y += v.y; acc.z += v.z; acc.w += v.w;
      }
    }
  }
  acc.x += __shfl_xor(acc.x, 16, 64); acc.y += __shfl_xor(acc.y, 16, 64);
  acc.z += __shfl_xor(acc.z, 16, 64); acc.w += __shfl_xor(acc.w, 16, 64);
  acc.x += __shfl_xor(acc.x, 32, 64); acc.y += __shfl_xor(acc.y, 32, 64);
  acc.z += __shfl_xor(acc.z, 32, 64); acc.w += __shfl_xor(acc.w, 32, 64);
  float dv = dinv[node];
  float4 res = make_float4(0.f, 0.f, 0.f, 0.f);
  if (fa){
    float4 b = ((const float4*)bc2)[fl];
    res.x = acc.x*dv + b.x;
    res.y = acc.y*dv + b.y;
    res.z = acc.z*dv + b.z;
    res.w = acc.w*dv + b.w;
  }
  if (mask[node] != 0){                    // wave-uniform branch
    float4 r;
    int j0 = fl*4;
    r.x = bds[(j0+0) < D_OUT ? j0+0 : 0];
    r.y = bds[(j0+1) < D_OUT ? j0+1 : 0];
    r.z = bds[(j0+2) < D_OUT ? j0+2 : 0];
    r.w = bds[(j0+3) < D_OUT ? j0+3 : 0];
    #pragma unroll
    for (int k4 = 0; k4 < 10; k4++){
      float ox = __shfl(res.x, k4, 64);    // sources are lanes 0..9 (valid res)
      float oy = __shfl(res.y, k4, 64);
      float oz = __shfl(res.z, k4, 64);
      float ow = __shfl(res.w, k4, 64);
      if (fa){
        int k = k4*4;
        const float* w0 = &wds[(j0+0)*41 + k];
        const float* w1 = &wds[(j0+1)*41 + k];
        const float* w2 = &wds[(j0+2)*41 + k];
        const float* w3 = &wds[(j0+3)*41 + k];
        r.x += ox*w0[0] + oy*w0[1] + oz*w0[2] + ow*w0[3];
        r.y += ox*w1[0] + oy*w1[1] + oz*w1[2] + ow*w1[3];
        r.z += ox*w2[0] + oy*w2[1] + oz*w2[2] + ow*w2[3];
        r.w += ox*w3[0] + oy*w3[1] + oz*w3[2] + ow*w3[3];
      }
    }
    if (fa) res = r;
  }
  if (grp == 0 && fa) ((float4*)out)[(size_t)node*10 + fl] = res;
}

// ---------------- launcher ----------------

extern "C" void kernel_launch(void* const* d_in, const int* in_sizes, int n_in,
                              void* d_out, int out_size, void* d_ws, size_t ws_size,
                              hipStream_t stream){
  const float* x    = (const float*)d_in[0];
  const int*   ei   = (const int*)d_in[1];
  const unsigned char* mask = (const unsigned char*)d_in[2];
  const float* Wc1  = (const float*)d_in[3];
  const float* bc1  = (const float*)d_in[4];
  const float* Wc2  = (const float*)d_in[5];
  const float* bc2  = (const float*)d_in[6];
  const float* Wd1  = (const float*)d_in[7];
  const float* bd1  = (const float*)d_in[8];
  const float* Wd2  = (const float*)d_in[9];
  const float* bd2  = (const float*)d_in[10];

  int N = in_sizes[0] / D_IN;
  int E = in_sizes[1] / 2;
  const int* src = ei;
  const int* dst = ei + E;
  float* out = (float*)d_out;

  char* w = (char*)d_ws; size_t off = 0;
  auto A = [&](size_t bytes)->void*{
    void* p = w + off;
    off += (bytes + 255) & ~(size_t)255;
    return p;
  };
  int*   deg    = (int*)  A((size_t)N*4);
  int*   rs     = (int*)  A((size_t)N*4);
  int*   cursor = (int*)  A((size_t)N*4);
  int*   bsums  = (int*)  A(256*4);
  float* dinv   = (float*)A((size_t)N*4);
  float* Mmat   = (float*)A((size_t)D_H*D_OUT*4);
  float* bvec   = (float*)A((size_t)D_OUT*4);
  int*   col    = (int*)  A((size_t)E*4);
  float* hws1   = (float*)A((size_t)N*D_H*4);
  float* h      = (float*)A((size_t)N*D_H*4);
  float* hws2   = hws1;   // hws1 dead after agg1 -> reuse

  int NB  = (N + 1023) / 1024;
  int EB8 = (E + 2047) / 2048;   // 8 edges per thread

  hipMemsetAsync(deg, 0, (size_t)N*4, stream);
  hipLaunchKernelGGL(k_count, dim3(EB8), dim3(256), 0, stream, dst, deg, E);
  hipLaunchKernelGGL(k_scan1, dim3(NB), dim3(1024), 0, stream, deg, rs, bsums, N);
  hipLaunchKernelGGL(k_scan2, dim3(1), dim3(128), 0, stream, bsums, NB);
  hipLaunchKernelGGL(k_scan3, dim3(NB), dim3(1024), 0, stream, deg, rs, bsums, cursor, dinv, N);
  hipLaunchKernelGGL(k_fill,  dim3(EB8), dim3(256), 0, stream, src, dst, cursor, col, E);
  hipLaunchKernelGGL(k_pre,   dim3(1), dim3(256), 0, stream, Wd1, bd1, Wc2, Mmat, bvec);
  hipLaunchKernelGGL(k_gemm1, dim3((N+31)/32), dim3(256), 0, stream, x, Wc1, dinv, hws1, N);
  hipLaunchKernelGGL(k_agg1,  dim3((N+3)/4), dim3(256), 0, stream, hws1, rs, deg, col, dinv, bc1, h, N);
  hipLaunchKernelGGL(k_gemm2, dim3((N+127)/128), dim3(128), 0, stream, h, mask, Mmat, bvec, Wc2, dinv, hws2, N);
  hipLaunchKernelGGL(k_agg2,  dim3((N+3)/4), dim3(256), 0, stream, hws2, rs, deg, col, dinv, bc2, mask, Wd2, bd2, out, N);
}

// Round 5
// 502.108 us; speedup vs baseline: 1.2080x; 1.2080x over previous
//
#include <hip/hip_runtime.h>

#define D_IN  128
#define D_H   64
#define D_OUT 40

// ---------------- CSR build: deg+pos in one atomic pass, then pure scatter ------

// pos[i] = rank of edge i within its dst segment (coalesced store; atomic return
// feeds a contiguous store, so no scattered dependent chain).
__launch_bounds__(256)
static __global__ void k_degpos(const int* __restrict__ dst, int* __restrict__ deg,
                                int* __restrict__ pos, int E){
  int base = (blockIdx.x*256 + threadIdx.x) * 4;
  if (base + 4 <= E){
    int4 d = *(const int4*)(dst + base);
    int4 p;
    p.x = atomicAdd(&deg[d.x], 1);
    p.y = atomicAdd(&deg[d.y], 1);
    p.z = atomicAdd(&deg[d.z], 1);
    p.w = atomicAdd(&deg[d.w], 1);
    *(int4*)(pos + base) = p;
  } else {
    for (int i = base; i < E; i++) pos[i] = atomicAdd(&deg[dst[i]], 1);
  }
}

static __global__ void k_scan1(const int* __restrict__ deg, int* __restrict__ incl,
                               int* __restrict__ bsums, int n){
  __shared__ int s[1024];
  int t = threadIdx.x; int g = blockIdx.x*1024 + t;
  int v = (g < n) ? deg[g] : 0;
  s[t] = v; __syncthreads();
  for (int off = 1; off < 1024; off <<= 1){
    int u = (t >= off) ? s[t-off] : 0; __syncthreads();
    s[t] += u; __syncthreads();
  }
  if (g < n) incl[g] = s[t];
  if (t == 1023) bsums[blockIdx.x] = s[1023];
}

static __global__ void k_scan2(int* bsums, int nb){
  __shared__ int s[128];
  int t = threadIdx.x;
  int v = (t < nb) ? bsums[t] : 0;
  s[t] = v; __syncthreads();
  for (int off = 1; off < 128; off <<= 1){
    int u = (t >= off) ? s[t-off] : 0; __syncthreads();
    s[t] += u; __syncthreads();
  }
  if (t < nb) bsums[t] = s[t] - v;   // exclusive block offsets
}

static __global__ void k_scan3(const int* __restrict__ deg, int* __restrict__ rs,
                               const int* __restrict__ bsums,
                               float* __restrict__ dinv, int n){
  int t = threadIdx.x; int g = blockIdx.x*1024 + t;
  if (g < n){
    int excl = rs[g] - deg[g] + bsums[blockIdx.x];
    rs[g] = excl;
    dinv[g] = rsqrtf((float)(deg[g] + 1));   // +1 = self loop
  }
}

// Pure fire-and-forget scatter: no atomics, no dependent chains between edges.
__launch_bounds__(256)
static __global__ void k_scatter(const int* __restrict__ src, const int* __restrict__ dst,
                                 const int* __restrict__ pos, const int* __restrict__ rs,
                                 int* __restrict__ col, int E){
  int base = (blockIdx.x*256 + threadIdx.x) * 4;
  if (base + 4 <= E){
    int4 d = *(const int4*)(dst + base);
    int4 s = *(const int4*)(src + base);
    int4 p = *(const int4*)(pos + base);
    col[rs[d.x] + p.x] = s.x;
    col[rs[d.y] + p.y] = s.y;
    col[rs[d.z] + p.z] = s.z;
    col[rs[d.w] + p.w] = s.w;
  } else {
    for (int i = base; i < E; i++) col[rs[dst[i]] + pos[i]] = src[i];
  }
}

// ---------------- fold delete-MLP into GEMM2: M = Wd1^T @ Wc2, bvec = bd1 @ Wc2 -----

static __global__ void k_pre(const float* __restrict__ Wd1, const float* __restrict__ bd1,
                             const float* __restrict__ Wc2, float* __restrict__ M,
                             float* __restrict__ bvec){
  int t = threadIdx.x;
  for (int i = t; i < D_H*D_OUT; i += 256){
    int q = i / D_OUT, j = i % D_OUT;
    float s = 0.f;
    for (int k = 0; k < D_H; k++) s += Wd1[k*D_H + q] * Wc2[k*D_OUT + j];
    M[i] = s;
  }
  if (t < D_OUT){
    float s = 0.f;
    for (int k = 0; k < D_H; k++) s += bd1[k] * Wc2[k*D_OUT + t];
    bvec[t] = s;
  }
}

// ---------------- GEMM1: hws1[n] = dinv[n] * (x[n] @ Wc1) ----------------

__launch_bounds__(256)
static __global__ void k_gemm1(const float* __restrict__ x, const float* __restrict__ Wc1,
                               const float* __restrict__ dinv, float* __restrict__ hws1, int n){
  __shared__ float Wl[D_IN*D_H];        // 32 KB
  __shared__ float xs[32][D_IN+1];      // padded
  int t = threadIdx.x;
  int base = blockIdx.x*32;
  for (int i = t; i < D_IN*D_H; i += 256) Wl[i] = Wc1[i];
  for (int i = t; i < 32*D_IN; i += 256){
    int r = i >> 7, c = i & 127;
    int node = base + r;
    xs[r][c] = (node < n) ? x[(size_t)node*D_IN + c] : 0.f;
  }
  __syncthreads();
  int nl = t >> 3, j0 = (t & 7)*8;
  int node = base + nl;
  if (node >= n) return;
  float acc[8] = {0,0,0,0,0,0,0,0};
  #pragma unroll 4
  for (int k = 0; k < D_IN; k++){
    float xv = xs[nl][k];
    #pragma unroll
    for (int jj = 0; jj < 8; jj++) acc[jj] += xv * Wl[k*D_H + j0 + jj];
  }
  float dv = dinv[node];
  float4 o0 = make_float4(acc[0]*dv, acc[1]*dv, acc[2]*dv, acc[3]*dv);
  float4 o1 = make_float4(acc[4]*dv, acc[5]*dv, acc[6]*dv, acc[7]*dv);
  float* op = hws1 + (size_t)node*D_H + j0;
  *(float4*)op = o0; *(float4*)(op+4) = o1;
}

// ---------------- agg1: h = relu(dinv * (self + sum_in) + bc1) ----------------
// 4 edges gathered per wave-instruction: 4 groups x 16 lanes x float4.

__launch_bounds__(256)
static __global__ void k_agg1(const float* __restrict__ hws1, const int* __restrict__ rs,
                              const int* __restrict__ deg, const int* __restrict__ col,
                              const float* __restrict__ dinv, const float* __restrict__ bc1,
                              float* __restrict__ h, int n){
  int t = threadIdx.x;
  int wave = t >> 6, lane = t & 63;
  int node = blockIdx.x*4 + wave;
  if (node >= n) return;
  int grp = lane >> 4, fl = lane & 15;
  const float4* h4 = (const float4*)hws1;
  float4 acc = make_float4(0.f, 0.f, 0.f, 0.f);
  if (grp == 0) acc = h4[(size_t)node*16 + fl];     // self loop
  int s0 = rs[node], cnt = deg[node];
  for (int cb = 0; cb < cnt; cb += 64){
    int m = cnt - cb; if (m > 64) m = 64;
    int idx = (lane < m) ? col[s0 + cb + lane] : 0;  // coalesced index prefetch
    #pragma unroll 4
    for (int e0 = 0; e0 < m; e0 += 4){
      int sl = e0 + grp;
      int s = __shfl(idx, sl, 64);
      if (sl < m){
        float4 v = h4[(size_t)s*16 + fl];
        acc.x += v.x; acc.y += v.y; acc.z += v.z; acc.w += v.w;
      }
    }
  }
  // combine the 4 groups
  acc.x += __shfl_xor(acc.x, 16, 64); acc.y += __shfl_xor(acc.y, 16, 64);
  acc.z += __shfl_xor(acc.z, 16, 64); acc.w += __shfl_xor(acc.w, 16, 64);
  acc.x += __shfl_xor(acc.x, 32, 64); acc.y += __shfl_xor(acc.y, 32, 64);
  acc.z += __shfl_xor(acc.z, 32, 64); acc.w += __shfl_xor(acc.w, 32, 64);
  if (grp == 0){
    float dv = dinv[node];
    float4 b = ((const float4*)bc1)[fl];
    float4 o;
    o.x = fmaxf(acc.x*dv + b.x, 0.f);
    o.y = fmaxf(acc.y*dv + b.y, 0.f);
    o.z = fmaxf(acc.z*dv + b.z, 0.f);
    o.w = fmaxf(acc.w*dv + b.w, 0.f);
    ((float4*)h)[(size_t)node*16 + fl] = o;
  }
}

// ---------------- GEMM2 (+ folded delete MLP): hws2[n] = dinv[n] * (h[n] @ (mask? M:Wc2)) --

__launch_bounds__(128)
static __global__ void k_gemm2(const float* __restrict__ h, const unsigned char* __restrict__ mask,
                               const float* __restrict__ Mmat, const float* __restrict__ bvec,
                               const float* __restrict__ Wc2, const float* __restrict__ dinv,
                               float* __restrict__ hws2, int n){
  __shared__ float Ms[D_H*D_OUT];          // 10 KB
  __shared__ float Ws[D_H*D_OUT];          // 10 KB
  __shared__ float bv[D_OUT];
  __shared__ float hs[128*(D_H+1)];        // 33.3 KB, padded stride 65
  int t = threadIdx.x;
  int base = blockIdx.x*128;
  for (int i = t; i < D_H*D_OUT; i += 128){ Ms[i] = Mmat[i]; Ws[i] = Wc2[i]; }
  if (t < D_OUT) bv[t] = bvec[t];
  for (int i = t; i < 128*D_H; i += 128){
    int r = i >> 6, c = i & 63;
    int node = base + r;
    hs[r*(D_H+1) + c] = (node < n) ? h[(size_t)node*D_H + c] : 0.f;
  }
  __syncthreads();
  int node = base + t;
  if (node >= n) return;
  bool m = mask[node] != 0;
  const float* Wp = m ? Ms : Ws;
  float acc[D_OUT];
  #pragma unroll
  for (int j = 0; j < D_OUT; j++) acc[j] = m ? bv[j] : 0.f;
  const float* hrow = &hs[t*(D_H+1)];
  for (int q = 0; q < D_H; q++){
    float hv = hrow[q];
    #pragma unroll
    for (int j = 0; j < D_OUT; j++) acc[j] += hv * Wp[q*D_OUT + j];
  }
  float dv = dinv[node];
  float* op = hws2 + (size_t)node*D_OUT;
  #pragma unroll
  for (int j = 0; j < D_OUT; j++) op[j] = acc[j]*dv;
}

// ---------------- agg2 + final delete epilogue -> out ----------------
// Same 4-edges-per-instruction structure; 10 of 16 lanes per group carry float4.

__launch_bounds__(256)
static __global__ void k_agg2(const float* __restrict__ hws2, const int* __restrict__ rs,
                              const int* __restrict__ deg, const int* __restrict__ col,
                              const float* __restrict__ dinv, const float* __restrict__ bc2,
                              const unsigned char* __restrict__ mask,
                              const float* __restrict__ Wd2, const float* __restrict__ bd2,
                              float* __restrict__ out, int n){
  __shared__ float wds[D_OUT*41];          // stride-41 pad -> <=2-way LDS conflict (free)
  __shared__ float bds[D_OUT];
  int t = threadIdx.x;
  for (int i = t; i < D_OUT*D_OUT; i += 256){
    int j = i / D_OUT, k = i % D_OUT;
    wds[j*41 + k] = Wd2[i];
  }
  if (t < D_OUT) bds[t] = bd2[t];
  __syncthreads();
  int wave = t >> 6, lane = t & 63;
  int node = blockIdx.x*4 + wave;
  if (node >= n) return;
  int grp = lane >> 4, fl = lane & 15;
  bool fa = fl < 10;                       // 10 float4 = 40 features
  const float4* h4 = (const float4*)hws2;
  float4 acc = make_float4(0.f, 0.f, 0.f, 0.f);
  if (grp == 0 && fa) acc = h4[(size_t)node*10 + fl];   // self loop
  int s0 = rs[node], cnt = deg[node];
  for (int cb = 0; cb < cnt; cb += 64){
    int m = cnt - cb; if (m > 64) m = 64;
    int idx = (lane < m) ? col[s0 + cb + lane] : 0;
    #pragma unroll 4
    for (int e0 = 0; e0 < m; e0 += 4){
      int sl = e0 + grp;
      int s = __shfl(idx, sl, 64);
      if (sl < m && fa){
        float4 v = h4[(size_t)s*10 + fl];
        acc.x += v.x; acc.y += v.y; acc.z += v.z; acc.w += v.w;
      }
    }
  }
  acc.x += __shfl_xor(acc.x, 16, 64); acc.y += __shfl_xor(acc.y, 16, 64);
  acc.z += __shfl_xor(acc.z, 16, 64); acc.w += __shfl_xor(acc.w, 16, 64);
  acc.x += __shfl_xor(acc.x, 32, 64); acc.y += __shfl_xor(acc.y, 32, 64);
  acc.z += __shfl_xor(acc.z, 32, 64); acc.w += __shfl_xor(acc.w, 32, 64);
  float dv = dinv[node];
  float4 res = make_float4(0.f, 0.f, 0.f, 0.f);
  if (fa){
    float4 b = ((const float4*)bc2)[fl];
    res.x = acc.x*dv + b.x;
    res.y = acc.y*dv + b.y;
    res.z = acc.z*dv + b.z;
    res.w = acc.w*dv + b.w;
  }
  if (mask[node] != 0){                    // wave-uniform branch
    float4 r;
    int j0 = fl*4;
    r.x = bds[(j0+0) < D_OUT ? j0+0 : 0];
    r.y = bds[(j0+1) < D_OUT ? j0+1 : 0];
    r.z = bds[(j0+2) < D_OUT ? j0+2 : 0];
    r.w = bds[(j0+3) < D_OUT ? j0+3 : 0];
    #pragma unroll
    for (int k4 = 0; k4 < 10; k4++){
      float ox = __shfl(res.x, k4, 64);    // sources are lanes 0..9 (valid res)
      float oy = __shfl(res.y, k4, 64);
      float oz = __shfl(res.z, k4, 64);
      float ow = __shfl(res.w, k4, 64);
      if (fa){
        int k = k4*4;
        const float* w0 = &wds[(j0+0)*41 + k];
        const float* w1 = &wds[(j0+1)*41 + k];
        const float* w2 = &wds[(j0+2)*41 + k];
        const float* w3 = &wds[(j0+3)*41 + k];
        r.x += ox*w0[0] + oy*w0[1] + oz*w0[2] + ow*w0[3];
        r.y += ox*w1[0] + oy*w1[1] + oz*w1[2] + ow*w1[3];
        r.z += ox*w2[0] + oy*w2[1] + oz*w2[2] + ow*w2[3];
        r.w += ox*w3[0] + oy*w3[1] + oz*w3[2] + ow*w3[3];
      }
    }
    if (fa) res = r;
  }
  if (grp == 0 && fa) ((float4*)out)[(size_t)node*10 + fl] = res;
}

// ---------------- launcher ----------------

extern "C" void kernel_launch(void* const* d_in, const int* in_sizes, int n_in,
                              void* d_out, int out_size, void* d_ws, size_t ws_size,
                              hipStream_t stream){
  const float* x    = (const float*)d_in[0];
  const int*   ei   = (const int*)d_in[1];
  const unsigned char* mask = (const unsigned char*)d_in[2];
  const float* Wc1  = (const float*)d_in[3];
  const float* bc1  = (const float*)d_in[4];
  const float* Wc2  = (const float*)d_in[5];
  const float* bc2  = (const float*)d_in[6];
  const float* Wd1  = (const float*)d_in[7];
  const float* bd1  = (const float*)d_in[8];
  const float* Wd2  = (const float*)d_in[9];
  const float* bd2  = (const float*)d_in[10];

  int N = in_sizes[0] / D_IN;
  int E = in_sizes[1] / 2;
  const int* src = ei;
  const int* dst = ei + E;
  float* out = (float*)d_out;

  char* w = (char*)d_ws; size_t off = 0;
  auto A = [&](size_t bytes)->void*{
    void* p = w + off;
    off += (bytes + 255) & ~(size_t)255;
    return p;
  };
  int*   deg    = (int*)  A((size_t)N*4);
  int*   rs     = (int*)  A((size_t)N*4);
  int*   bsums  = (int*)  A(256*4);
  float* dinv   = (float*)A((size_t)N*4);
  float* Mmat   = (float*)A((size_t)D_H*D_OUT*4);
  float* bvec   = (float*)A((size_t)D_OUT*4);
  int*   col    = (int*)  A((size_t)E*4);
  float* hws1   = (float*)A((size_t)N*D_H*4);
  float* h      = (float*)A((size_t)N*D_H*4);
  float* hws2   = hws1;        // hws1 dead after agg1 -> reuse
  int*   pos    = (int*)hws1;  // pos dead before gemm1 writes hws1 -> alias

  int NB  = (N + 1023) / 1024;
  int EB4 = (E + 1023) / 1024;   // 4 edges per thread

  hipMemsetAsync(deg, 0, (size_t)N*4, stream);
  hipLaunchKernelGGL(k_degpos, dim3(EB4), dim3(256), 0, stream, dst, deg, pos, E);
  hipLaunchKernelGGL(k_scan1, dim3(NB), dim3(1024), 0, stream, deg, rs, bsums, N);
  hipLaunchKernelGGL(k_scan2, dim3(1), dim3(128), 0, stream, bsums, NB);
  hipLaunchKernelGGL(k_scan3, dim3(NB), dim3(1024), 0, stream, deg, rs, bsums, dinv, N);
  hipLaunchKernelGGL(k_scatter, dim3(EB4), dim3(256), 0, stream, src, dst, pos, rs, col, E);
  hipLaunchKernelGGL(k_pre,   dim3(1), dim3(256), 0, stream, Wd1, bd1, Wc2, Mmat, bvec);
  hipLaunchKernelGGL(k_gemm1, dim3((N+31)/32), dim3(256), 0, stream, x, Wc1, dinv, hws1, N);
  hipLaunchKernelGGL(k_agg1,  dim3((N+3)/4), dim3(256), 0, stream, hws1, rs, deg, col, dinv, bc1, h, N);
  hipLaunchKernelGGL(k_gemm2, dim3((N+127)/128), dim3(128), 0, stream, h, mask, Mmat, bvec, Wc2, dinv, hws2, N);
  hipLaunchKernelGGL(k_agg2,  dim3((N+3)/4), dim3(256), 0, stream, hws2, rs, deg, col, dinv, bc2, mask, Wd2, bd2, out, N);
}

// Round 7
// 494.461 us; speedup vs baseline: 1.2267x; 1.0155x over previous
//
#include <hip/hip_runtime.h>

#define D_IN  128
#define D_H   64
#define D_OUT 40

// ---- bf16 helpers (bit ops; RTNE pack) ----
__device__ __forceinline__ float bf_lo(unsigned u){ return __uint_as_float(u << 16); }
__device__ __forceinline__ float bf_hi(unsigned u){ return __uint_as_float(u & 0xFFFF0000u); }
__device__ __forceinline__ unsigned bf_pack(float a, float b){
  unsigned ua = __float_as_uint(a), ub = __float_as_uint(b);
  unsigned lo = (ua + 0x7FFFu + ((ua >> 16) & 1u)) >> 16;
  unsigned hi = (ub + 0x7FFFu + ((ub >> 16) & 1u)) & 0xFFFF0000u;
  return hi | lo;
}

// ---------------- CSR build: deg+pos in one atomic pass, then pure scatter ------

__launch_bounds__(256)
static __global__ void k_degpos(const int* __restrict__ dst, int* __restrict__ deg,
                                int* __restrict__ pos, int E){
  int base = (blockIdx.x*256 + threadIdx.x) * 4;
  if (base + 4 <= E){
    int4 d = *(const int4*)(dst + base);
    int4 p;
    p.x = atomicAdd(&deg[d.x], 1);
    p.y = atomicAdd(&deg[d.y], 1);
    p.z = atomicAdd(&deg[d.z], 1);
    p.w = atomicAdd(&deg[d.w], 1);
    *(int4*)(pos + base) = p;
  } else {
    for (int i = base; i < E; i++) pos[i] = atomicAdd(&deg[dst[i]], 1);
  }
}

static __global__ void k_scan1(const int* __restrict__ deg, int* __restrict__ incl,
                               int* __restrict__ bsums, int n){
  __shared__ int s[1024];
  int t = threadIdx.x; int g = blockIdx.x*1024 + t;
  int v = (g < n) ? deg[g] : 0;
  s[t] = v; __syncthreads();
  for (int off = 1; off < 1024; off <<= 1){
    int u = (t >= off) ? s[t-off] : 0; __syncthreads();
    s[t] += u; __syncthreads();
  }
  if (g < n) incl[g] = s[t];
  if (t == 1023) bsums[blockIdx.x] = s[1023];
}

static __global__ void k_scan2(int* bsums, int nb){
  __shared__ int s[128];
  int t = threadIdx.x;
  int v = (t < nb) ? bsums[t] : 0;
  s[t] = v; __syncthreads();
  for (int off = 1; off < 128; off <<= 1){
    int u = (t >= off) ? s[t-off] : 0; __syncthreads();
    s[t] += u; __syncthreads();
  }
  if (t < nb) bsums[t] = s[t] - v;   // exclusive block offsets
}

static __global__ void k_scan3(const int* __restrict__ deg, int* __restrict__ rs,
                               const int* __restrict__ bsums,
                               float* __restrict__ dinv, int n){
  int t = threadIdx.x; int g = blockIdx.x*1024 + t;
  if (g < n){
    int excl = rs[g] - deg[g] + bsums[blockIdx.x];
    rs[g] = excl;
    dinv[g] = rsqrtf((float)(deg[g] + 1));   // +1 = self loop
  }
}

__launch_bounds__(256)
static __global__ void k_scatter(const int* __restrict__ src, const int* __restrict__ dst,
                                 const int* __restrict__ pos, const int* __restrict__ rs,
                                 int* __restrict__ col, int E){
  int base = (blockIdx.x*256 + threadIdx.x) * 4;
  if (base + 4 <= E){
    int4 d = *(const int4*)(dst + base);
    int4 s = *(const int4*)(src + base);
    int4 p = *(const int4*)(pos + base);
    col[rs[d.x] + p.x] = s.x;
    col[rs[d.y] + p.y] = s.y;
    col[rs[d.z] + p.z] = s.z;
    col[rs[d.w] + p.w] = s.w;
  } else {
    for (int i = base; i < E; i++) col[rs[dst[i]] + pos[i]] = src[i];
  }
}

// ---------------- fold delete-MLP into GEMM2: M = Wd1^T @ Wc2, bvec = bd1 @ Wc2 -----

static __global__ void k_pre(const float* __restrict__ Wd1, const float* __restrict__ bd1,
                             const float* __restrict__ Wc2, float* __restrict__ M,
                             float* __restrict__ bvec){
  int t = threadIdx.x;
  for (int i = t; i < D_H*D_OUT; i += 256){
    int q = i / D_OUT, j = i % D_OUT;
    float s = 0.f;
    for (int k = 0; k < D_H; k++) s += Wd1[k*D_H + q] * Wc2[k*D_OUT + j];
    M[i] = s;
  }
  if (t < D_OUT){
    float s = 0.f;
    for (int k = 0; k < D_H; k++) s += bd1[k] * Wc2[k*D_OUT + t];
    bvec[t] = s;
  }
}

// ---------------- GEMM1: hws1b[n] = bf16( dinv[n] * (x[n] @ Wc1) ) ----------------

__launch_bounds__(256)
static __global__ void k_gemm1(const float* __restrict__ x, const float* __restrict__ Wc1,
                               const float* __restrict__ dinv,
                               unsigned short* __restrict__ hws1b, int n){
  __shared__ float Wl[D_IN*D_H];        // 32 KB
  __shared__ float xs[32][D_IN+1];      // padded
  int t = threadIdx.x;
  int base = blockIdx.x*32;
  for (int i = t; i < D_IN*D_H; i += 256) Wl[i] = Wc1[i];
  for (int i = t; i < 32*D_IN; i += 256){
    int r = i >> 7, c = i & 127;
    int node = base + r;
    xs[r][c] = (node < n) ? x[(size_t)node*D_IN + c] : 0.f;
  }
  __syncthreads();
  int nl = t >> 3, j0 = (t & 7)*8;
  int node = base + nl;
  if (node >= n) return;
  float acc[8] = {0,0,0,0,0,0,0,0};
  #pragma unroll 4
  for (int k = 0; k < D_IN; k++){
    float xv = xs[nl][k];
    #pragma unroll
    for (int jj = 0; jj < 8; jj++) acc[jj] += xv * Wl[k*D_H + j0 + jj];
  }
  float dv = dinv[node];
  uint4 o;
  o.x = bf_pack(acc[0]*dv, acc[1]*dv);
  o.y = bf_pack(acc[2]*dv, acc[3]*dv);
  o.z = bf_pack(acc[4]*dv, acc[5]*dv);
  o.w = bf_pack(acc[6]*dv, acc[7]*dv);
  *(uint4*)(hws1b + (size_t)node*D_H + j0) = o;   // byte off = node*128 + j0*2 (16B aligned)
}

// ---------------- agg1: h = relu(dinv * (self + sum_in) + bc1) ----------------
// 4 edges per wave-instruction: 4 groups x 16 lanes x uint2 (4 bf16 each).

__launch_bounds__(256)
static __global__ void k_agg1(const unsigned short* __restrict__ hws1b, const int* __restrict__ rs,
                              const int* __restrict__ deg, const int* __restrict__ col,
                              const float* __restrict__ dinv, const float* __restrict__ bc1,
                              float* __restrict__ h, int n){
  int t = threadIdx.x;
  int wave = t >> 6, lane = t & 63;
  int node = blockIdx.x*4 + wave;
  if (node >= n) return;
  int grp = lane >> 4, fl = lane & 15;
  const uint2* g2 = (const uint2*)hws1b;           // row = 16 uint2
  float a0=0.f, a1=0.f, a2=0.f, a3=0.f;
  if (grp == 0){
    uint2 v = g2[(size_t)node*16 + fl];            // self loop
    a0 += bf_lo(v.x); a1 += bf_hi(v.x); a2 += bf_lo(v.y); a3 += bf_hi(v.y);
  }
  int s0 = rs[node], cnt = deg[node];
  for (int cb = 0; cb < cnt; cb += 64){
    int m = cnt - cb; if (m > 64) m = 64;
    int idx = (lane < m) ? col[s0 + cb + lane] : 0;  // coalesced index prefetch
    #pragma unroll 4
    for (int e0 = 0; e0 < m; e0 += 4){
      int sl = e0 + grp;
      int s = __shfl(idx, sl, 64);
      if (sl < m){
        uint2 v = g2[(size_t)s*16 + fl];
        a0 += bf_lo(v.x); a1 += bf_hi(v.x); a2 += bf_lo(v.y); a3 += bf_hi(v.y);
      }
    }
  }
  a0 += __shfl_xor(a0, 16, 64); a1 += __shfl_xor(a1, 16, 64);
  a2 += __shfl_xor(a2, 16, 64); a3 += __shfl_xor(a3, 16, 64);
  a0 += __shfl_xor(a0, 32, 64); a1 += __shfl_xor(a1, 32, 64);
  a2 += __shfl_xor(a2, 32, 64); a3 += __shfl_xor(a3, 32, 64);
  if (grp == 0){
    float dv = dinv[node];
    float4 b = ((const float4*)bc1)[fl];
    float4 o;
    o.x = fmaxf(a0*dv + b.x, 0.f);
    o.y = fmaxf(a1*dv + b.y, 0.f);
    o.z = fmaxf(a2*dv + b.z, 0.f);
    o.w = fmaxf(a3*dv + b.w, 0.f);
    ((float4*)h)[(size_t)node*16 + fl] = o;
  }
}

// ---------------- GEMM2 (+ folded delete MLP): hws2b[n] = bf16(dinv * (h @ (mask?M:Wc2))) --

__launch_bounds__(128)
static __global__ void k_gemm2(const float* __restrict__ h, const unsigned char* __restrict__ mask,
                               const float* __restrict__ Mmat, const float* __restrict__ bvec,
                               const float* __restrict__ Wc2, const float* __restrict__ dinv,
                               unsigned short* __restrict__ hws2b, int n){
  __shared__ float Ms[D_H*D_OUT];          // 10 KB
  __shared__ float Ws[D_H*D_OUT];          // 10 KB
  __shared__ float bv[D_OUT];
  __shared__ float hs[128*(D_H+1)];        // 33.3 KB, padded stride 65
  int t = threadIdx.x;
  int base = blockIdx.x*128;
  for (int i = t; i < D_H*D_OUT; i += 128){ Ms[i] = Mmat[i]; Ws[i] = Wc2[i]; }
  if (t < D_OUT) bv[t] = bvec[t];
  for (int i = t; i < 128*D_H; i += 128){
    int r = i >> 6, c = i & 63;
    int node = base + r;
    hs[r*(D_H+1) + c] = (node < n) ? h[(size_t)node*D_H + c] : 0.f;
  }
  __syncthreads();
  int node = base + t;
  if (node >= n) return;
  bool m = mask[node] != 0;
  const float* Wp = m ? Ms : Ws;
  float acc[D_OUT];
  #pragma unroll
  for (int j = 0; j < D_OUT; j++) acc[j] = m ? bv[j] : 0.f;
  const float* hrow = &hs[t*(D_H+1)];
  for (int q = 0; q < D_H; q++){
    float hv = hrow[q];
    #pragma unroll
    for (int j = 0; j < D_OUT; j++) acc[j] += hv * Wp[q*D_OUT + j];
  }
  float dv = dinv[node];
  unsigned short* op = hws2b + (size_t)node*D_OUT;   // byte off = node*80 (16B aligned)
  #pragma unroll
  for (int k = 0; k < 5; k++){
    uint4 o;
    o.x = bf_pack(acc[k*8+0]*dv, acc[k*8+1]*dv);
    o.y = bf_pack(acc[k*8+2]*dv, acc[k*8+3]*dv);
    o.z = bf_pack(acc[k*8+4]*dv, acc[k*8+5]*dv);
    o.w = bf_pack(acc[k*8+6]*dv, acc[k*8+7]*dv);
    *(uint4*)(op + k*8) = o;
  }
}

// ---------------- agg2 + final delete epilogue -> out ----------------
// 10 of 16 lanes per group carry uint2 (4 bf16); same element mapping as before.

__launch_bounds__(256)
static __global__ void k_agg2(const unsigned short* __restrict__ hws2b, const int* __restrict__ rs,
                              const int* __restrict__ deg, const int* __restrict__ col,
                              const float* __restrict__ dinv, const float* __restrict__ bc2,
                              const unsigned char* __restrict__ mask,
                              const float* __restrict__ Wd2, const float* __restrict__ bd2,
                              float* __restrict__ out, int n){
  __shared__ float wds[D_OUT*41];          // stride-41 pad -> <=2-way LDS conflict (free)
  __shared__ float bds[D_OUT];
  int t = threadIdx.x;
  for (int i = t; i < D_OUT*D_OUT; i += 256){
    int j = i / D_OUT, k = i % D_OUT;
    wds[j*41 + k] = Wd2[i];
  }
  if (t < D_OUT) bds[t] = bd2[t];
  __syncthreads();
  int wave = t >> 6, lane = t & 63;
  int node = blockIdx.x*4 + wave;
  if (node >= n) return;
  int grp = lane >> 4, fl = lane & 15;
  bool fa = fl < 10;                       // 10 uint2 = 40 bf16
  const uint2* g2 = (const uint2*)hws2b;   // row = 10 uint2
  float a0=0.f, a1=0.f, a2=0.f, a3=0.f;
  if (grp == 0 && fa){
    uint2 v = g2[(size_t)node*10 + fl];    // self loop
    a0 += bf_lo(v.x); a1 += bf_hi(v.x); a2 += bf_lo(v.y); a3 += bf_hi(v.y);
  }
  int s0 = rs[node], cnt = deg[node];
  for (int cb = 0; cb < cnt; cb += 64){
    int m = cnt - cb; if (m > 64) m = 64;
    int idx = (lane < m) ? col[s0 + cb + lane] : 0;
    #pragma unroll 4
    for (int e0 = 0; e0 < m; e0 += 4){
      int sl = e0 + grp;
      int s = __shfl(idx, sl, 64);
      if (sl < m && fa){
        uint2 v = g2[(size_t)s*10 + fl];
        a0 += bf_lo(v.x); a1 += bf_hi(v.x); a2 += bf_lo(v.y); a3 += bf_hi(v.y);
      }
    }
  }
  a0 += __shfl_xor(a0, 16, 64); a1 += __shfl_xor(a1, 16, 64);
  a2 += __shfl_xor(a2, 16, 64); a3 += __shfl_xor(a3, 16, 64);
  a0 += __shfl_xor(a0, 32, 64); a1 += __shfl_xor(a1, 32, 64);
  a2 += __shfl_xor(a2, 32, 64); a3 += __shfl_xor(a3, 32, 64);
  float dv = dinv[node];
  float4 res = make_float4(0.f, 0.f, 0.f, 0.f);
  if (fa){
    float4 b = ((const float4*)bc2)[fl];
    res.x = a0*dv + b.x;
    res.y = a1*dv + b.y;
    res.z = a2*dv + b.z;
    res.w = a3*dv + b.w;
  }
  if (mask[node] != 0){                    // wave-uniform branch
    float4 r;
    int j0 = fl*4;
    r.x = bds[(j0+0) < D_OUT ? j0+0 : 0];
    r.y = bds[(j0+1) < D_OUT ? j0+1 : 0];
    r.z = bds[(j0+2) < D_OUT ? j0+2 : 0];
    r.w = bds[(j0+3) < D_OUT ? j0+3 : 0];
    #pragma unroll
    for (int k4 = 0; k4 < 10; k4++){
      float ox = __shfl(res.x, k4, 64);    // sources are lanes 0..9 (valid res)
      float oy = __shfl(res.y, k4, 64);
      float oz = __shfl(res.z, k4, 64);
      float ow = __shfl(res.w, k4, 64);
      if (fa){
        int k = k4*4;
        const float* w0 = &wds[(j0+0)*41 + k];
        const float* w1 = &wds[(j0+1)*41 + k];
        const float* w2 = &wds[(j0+2)*41 + k];
        const float* w3 = &wds[(j0+3)*41 + k];
        r.x += ox*w0[0] + oy*w0[1] + oz*w0[2] + ow*w0[3];
        r.y += ox*w1[0] + oy*w1[1] + oz*w1[2] + ow*w1[3];
        r.z += ox*w2[0] + oy*w2[1] + oz*w2[2] + ow*w2[3];
        r.w += ox*w3[0] + oy*w3[1] + oz*w3[2] + ow*w3[3];
      }
    }
    if (fa) res = r;
  }
  if (grp == 0 && fa) ((float4*)out)[(size_t)node*10 + fl] = res;
}

// ---------------- launcher ----------------

extern "C" void kernel_launch(void* const* d_in, const int* in_sizes, int n_in,
                              void* d_out, int out_size, void* d_ws, size_t ws_size,
                              hipStream_t stream){
  const float* x    = (const float*)d_in[0];
  const int*   ei   = (const int*)d_in[1];
  const unsigned char* mask = (const unsigned char*)d_in[2];
  const float* Wc1  = (const float*)d_in[3];
  const float* bc1  = (const float*)d_in[4];
  const float* Wc2  = (const float*)d_in[5];
  const float* bc2  = (const float*)d_in[6];
  const float* Wd1  = (const float*)d_in[7];
  const float* bd1  = (const float*)d_in[8];
  const float* Wd2  = (const float*)d_in[9];
  const float* bd2  = (const float*)d_in[10];

  int N = in_sizes[0] / D_IN;
  int E = in_sizes[1] / 2;
  const int* src = ei;
  const int* dst = ei + E;
  float* out = (float*)d_out;

  char* w = (char*)d_ws; size_t off = 0;
  auto A = [&](size_t bytes)->void*{
    void* p = w + off;
    off += (bytes + 255) & ~(size_t)255;
    return p;
  };
  int*   deg    = (int*)  A((size_t)N*4);
  int*   rs     = (int*)  A((size_t)N*4);
  int*   bsums  = (int*)  A(256*4);
  float* dinv   = (float*)A((size_t)N*4);
  float* Mmat   = (float*)A((size_t)D_H*D_OUT*4);
  float* bvec   = (float*)A((size_t)D_OUT*4);
  int*   col    = (int*)  A((size_t)E*4);
  unsigned short* hws1b = (unsigned short*)A((size_t)N*D_H*2);   // 12.8 MB
  float* h      = (float*)A((size_t)N*D_H*4);
  unsigned short* hws2b = hws1b;   // hws1b dead after agg1 -> reuse (8 MB < 12.8 MB)
  int*   pos    = (int*)hws1b;     // pos (6.4 MB) dead before gemm1 writes hws1b

  int NB  = (N + 1023) / 1024;
  int EB4 = (E + 1023) / 1024;   // 4 edges per thread

  hipMemsetAsync(deg, 0, (size_t)N*4, stream);
  hipLaunchKernelGGL(k_degpos, dim3(EB4), dim3(256), 0, stream, dst, deg, pos, E);
  hipLaunchKernelGGL(k_scan1, dim3(NB), dim3(1024), 0, stream, deg, rs, bsums, N);
  hipLaunchKernelGGL(k_scan2, dim3(1), dim3(128), 0, stream, bsums, NB);
  hipLaunchKernelGGL(k_scan3, dim3(NB), dim3(1024), 0, stream, deg, rs, bsums, dinv, N);
  hipLaunchKernelGGL(k_scatter, dim3(EB4), dim3(256), 0, stream, src, dst, pos, rs, col, E);
  hipLaunchKernelGGL(k_pre,   dim3(1), dim3(256), 0, stream, Wd1, bd1, Wc2, Mmat, bvec);
  hipLaunchKernelGGL(k_gemm1, dim3((N+31)/32), dim3(256), 0, stream, x, Wc1, dinv, hws1b, N);
  hipLaunchKernelGGL(k_agg1,  dim3((N+3)/4), dim3(256), 0, stream, hws1b, rs, deg, col, dinv, bc1, h, N);
  hipLaunchKernelGGL(k_gemm2, dim3((N+127)/128), dim3(128), 0, stream, h, mask, Mmat, bvec, Wc2, dinv, hws2b, N);
  hipLaunchKernelGGL(k_agg2,  dim3((N+3)/4), dim3(256), 0, stream, hws2b, rs, deg, col, dinv, bc2, mask, Wd2, bd2, out, N);
}